// Round 8
// baseline (119.815 us; speedup 1.0000x reference)
//
#include <hip/hip_runtime.h>

#define BQ 32
#define H  128
#define C  512
#define D  128

typedef _Float16 half8v __attribute__((ext_vector_type(8)));
typedef float floatx4 __attribute__((ext_vector_type(4)));

#define FLAG_V   0x13579BDFu
#define FLAG_MAG 0xDEADBEEFu

// ---------------------------------------------------------------------------
// Kernel 0: Q fp32 -> fp16 fragments + zero loss accumulator.
// BYTE-IDENTICAL to the 93.8us baseline.
// Frag index (half8 units): ((b*4 + kb)*2 + sh)*64 + lane
// ---------------------------------------------------------------------------
__global__ __launch_bounds__(256) void qprep_kernel(const float* __restrict__ q,
                                                    _Float16* __restrict__ qs,
                                                    float* __restrict__ out) {
  int t = blockIdx.x * 256 + threadIdx.x;
  if (t == 0) out[0] = 0.0f;
  int lane = t & 63;
  int sh   = (t >> 6) & 1;
  int kb   = (t >> 7) & 3;
  int b    = t >> 9;
  int s    = sh * 16 + (lane & 15);
  int h    = kb * 32 + (lane >> 4) * 8;
  const float* src = q + ((b * 32 + s) * H + h);
  float4 v0 = *(const float4*)src;
  float4 v1 = *(const float4*)(src + 4);
  half8v o = { (_Float16)v0.x, (_Float16)v0.y, (_Float16)v0.z, (_Float16)v0.w,
               (_Float16)v1.x, (_Float16)v1.y, (_Float16)v1.z, (_Float16)v1.w };
  *(half8v*)(qs + (size_t)t * 8) = o;
}

// ---------------------------------------------------------------------------
// Kernel 1 (fused): grid 513 x 256.
// Blocks 0..511: VERBATIM r0/93.8us scores body (4 waves, dq/sh roles, fp16
//   qb[3] ring at distance 2 -- the only Q transport with proven codegen;
//   r2/r3/r4 alternatives all collapsed regalloc).  After the score stores:
//   device fence + release flag-pair (r4-proven protocol, absmax 0).
// Block 512: spins on the 512 flag pairs (init-free: poison (P,P) gives
//   P^P=0 != MAGIC, so the harness re-poison IS the reset; producers never
//   wait => deadlock-free; 513th block co-residency not required), then
//   computes the loss (r4-proven body, bit-identical sum order).
// Saves one regular-launch boundary (~7-11us per r2/r4 accounting) and
// overlaps the loss tail with the scores drain.
// ---------------------------------------------------------------------------
__global__ __launch_bounds__(256, 2) void fused_kernel(const float* __restrict__ pos,
                                                       const _Float16* __restrict__ qs,
                                                       float* __restrict__ scores,
                                                       unsigned int* __restrict__ flags,
                                                       float* __restrict__ out) {
  const int tid  = threadIdx.x;
  const int w    = tid >> 6;
  const int lane = tid & 63;

  __shared__ float pmm[BQ][4][16];   // 8 KB (loss block reuses as red[])

  if (blockIdx.x < C) {
    // ================= scores block (verbatim r0) =================
    const int c    = blockIdx.x;
    const int dq   = w & 1;            // d-half
    const int sh   = w >> 1;           // s-half
    const int quad = lane >> 4;
    const int nrow = lane & 15;

    const half8v* qf = (const half8v*)qs;
    const float*  pc = pos + (size_t)c * (D * H);

    half8v  pa[4][4];    // P_c A-frags [mt][kb]  (64 VGPRs)
    half8v  qb[3][4];    // Q B-frags, round-robin, prefetch distance 2 (48 VGPRs)
    floatx4 acc[2][4];   // [buf][mt] (32 VGPRs)
    floatx4 zc = {0.f, 0.f, 0.f, 0.f};

    // P_c A-frags: A[m = dq*64 + mt*16 + nrow][k = kb*32 + quad*8 + j]
#pragma unroll
    for (int kb = 0; kb < 4; ++kb)
#pragma unroll
      for (int mt = 0; mt < 4; ++mt) {
        const float* src = pc + ((dq * 64 + mt * 16 + nrow) * H + kb * 32 + quad * 8);
        float4 v0 = *(const float4*)src;
        float4 v1 = *(const float4*)(src + 4);
        half8v f = { (_Float16)v0.x, (_Float16)v0.y, (_Float16)v0.z, (_Float16)v0.w,
                     (_Float16)v1.x, (_Float16)v1.y, (_Float16)v1.z, (_Float16)v1.w };
        pa[mt][kb] = f;
      }

    // Q fragments for b=0,1 (prefetch pipeline primed to depth 2)
#pragma unroll
    for (int kb = 0; kb < 4; ++kb) qb[0][kb] = qf[(kb * 2 + sh) * 64 + lane];
#pragma unroll
    for (int kb = 0; kb < 4; ++kb) qb[1][kb] = qf[((4 + kb) * 2 + sh) * 64 + lane];

    // C/D: col s_local = lane&15, row d_local = quad*4 + r  [m89/m91]
    auto reduce_store = [&](int b, floatx4 (&a)[4]) {
      float m0 = fmaxf(fmaxf(a[0][0], a[0][1]), fmaxf(a[0][2], a[0][3]));
      float m1 = fmaxf(fmaxf(a[1][0], a[1][1]), fmaxf(a[1][2], a[1][3]));
      float m2 = fmaxf(fmaxf(a[2][0], a[2][1]), fmaxf(a[2][2], a[2][3]));
      float m3 = fmaxf(fmaxf(a[3][0], a[3][1]), fmaxf(a[3][2], a[3][3]));
      float m  = fmaxf(fmaxf(m0, m1), fmaxf(m2, m3));
      m = fmaxf(m, __shfl_xor(m, 16));
      m = fmaxf(m, __shfl_xor(m, 32));
      if (lane < 16) pmm[b][w][lane] = m;
    };

    // main loop: prefetch b+2 (distance 2), compute b, reduce b-1
#pragma unroll
    for (int b = 0; b < BQ; ++b) {
      const int cur = b & 1;
      if (b + 2 < BQ) {
        half8v* dst = qb[(b + 2) % 3];
#pragma unroll
        for (int kb = 0; kb < 4; ++kb) dst[kb] = qf[(((b + 2) * 4 + kb) * 2 + sh) * 64 + lane];
      }
      const half8v* qc = qb[b % 3];
#pragma unroll
      for (int mt = 0; mt < 4; ++mt)
        acc[cur][mt] = __builtin_amdgcn_mfma_f32_16x16x32_f16(pa[mt][0], qc[0], zc, 0, 0, 0);
#pragma unroll
      for (int kb = 1; kb < 4; ++kb)
#pragma unroll
        for (int mt = 0; mt < 4; ++mt)
          acc[cur][mt] = __builtin_amdgcn_mfma_f32_16x16x32_f16(pa[mt][kb], qc[kb], acc[cur][mt], 0, 0, 0);
      if (b > 0) reduce_store(b - 1, acc[cur ^ 1]);
    }
    reduce_store(BQ - 1, acc[1]);   // b=31 landed in acc[1]

    __syncthreads();

    // epilogue: scores[b][c] = 50 * sum_s max over the two d-half waves
    {
      int b  = tid >> 3;
      int t8 = tid & 7;
      float v = 0.f;
#pragma unroll
      for (int j = 0; j < 4; ++j) {
        int s  = t8 * 4 + j;
        int h2 = s >> 4, sl = s & 15;
        v += fmaxf(pmm[b][2 * h2][sl], pmm[b][2 * h2 + 1][sl]);
      }
      v += __shfl_xor(v, 1);
      v += __shfl_xor(v, 2);
      v += __shfl_xor(v, 4);
      if (t8 == 0) scores[b * C + c] = v * 50.0f;   // / TEMPERATURE
    }

    // publish: score stores drained by __syncthreads (vmcnt(0)), then device
    // fence + release flag pair (r4-proven).
    __syncthreads();
    if (tid == 0) {
      __threadfence();
      __hip_atomic_store(flags + 2 * c,     FLAG_V,            __ATOMIC_RELEASE, __HIP_MEMORY_SCOPE_AGENT);
      __hip_atomic_store(flags + 2 * c + 1, FLAG_V ^ FLAG_MAG, __ATOMIC_RELEASE, __HIP_MEMORY_SCOPE_AGENT);
    }
  } else {
    // ================= loss block (spin consumer, verbatim r4) =================
    const int c0 = tid * 2;          // each thread owns flags for c0, c0+1
    unsigned int f0, f1;
    do {
      f0 = __hip_atomic_load(flags + 2 * c0,     __ATOMIC_RELAXED, __HIP_MEMORY_SCOPE_AGENT);
      f1 = __hip_atomic_load(flags + 2 * c0 + 1, __ATOMIC_RELAXED, __HIP_MEMORY_SCOPE_AGENT);
      if ((f0 ^ f1) != FLAG_MAG) __builtin_amdgcn_s_sleep(2);
    } while ((f0 ^ f1) != FLAG_MAG);
    do {
      f0 = __hip_atomic_load(flags + 2 * c0 + 2, __ATOMIC_RELAXED, __HIP_MEMORY_SCOPE_AGENT);
      f1 = __hip_atomic_load(flags + 2 * c0 + 3, __ATOMIC_RELAXED, __HIP_MEMORY_SCOPE_AGENT);
      if ((f0 ^ f1) != FLAG_MAG) __builtin_amdgcn_s_sleep(2);
    } while ((f0 ^ f1) != FLAG_MAG);
    __syncthreads();
    __threadfence();                 // acquire: order flag reads before score reads

    // r4-proven loss math: 4 waves x 2 virtual passes, bit-identical order
    float* red = (float*)pmm;
    float part0 = 0.f, part1 = 0.f;
#pragma unroll
    for (int half = 0; half < 2; ++half)
#pragma unroll
      for (int i = 0; i < 4; ++i) {
        const int b = (w + half * 4) * 4 + i;
        const float* row = scores + b * C;
        const float4* r4 = (const float4*)row;
        float4 v0 = r4[lane * 2];
        float4 v1 = r4[lane * 2 + 1];
        float mx = fmaxf(fmaxf(fmaxf(v0.x, v0.y), fmaxf(v0.z, v0.w)),
                         fmaxf(fmaxf(v1.x, v1.y), fmaxf(v1.z, v1.w)));
#pragma unroll
        for (int off = 1; off < 64; off <<= 1) mx = fmaxf(mx, __shfl_xor(mx, off));
        float e = __expf(v0.x - mx) + __expf(v0.y - mx) + __expf(v0.z - mx) + __expf(v0.w - mx)
                + __expf(v1.x - mx) + __expf(v1.y - mx) + __expf(v1.z - mx) + __expf(v1.w - mx);
#pragma unroll
        for (int off = 1; off < 64; off <<= 1) e += __shfl_xor(e, off);
        if (lane == 0) {
          float t = mx + __logf(e) - row[0];
          if (half == 0) part0 += t; else part1 += t;
        }
      }
    if (lane == 0) { red[w] = part0; red[w + 4] = part1; }
    __syncthreads();
    if (tid == 0) {
      float s = red[0] + red[1] + red[2] + red[3] + red[4] + red[5] + red[6] + red[7];
      out[0] = s * (1.0f / 32.0f);
    }
  }
}

extern "C" void kernel_launch(void* const* d_in, const int* in_sizes, int n_in,
                              void* d_out, int out_size, void* d_ws, size_t ws_size,
                              hipStream_t stream) {
  const float* q = (const float*)d_in[0];   // [32,32,128] fp32
  const float* p = (const float*)d_in[1];   // [512,128,128] fp32
  float* scores  = (float*)d_ws;                                   // 64 KB
  _Float16* qs   = (_Float16*)((char*)d_ws + 65536);               // 256 KB fp16 frags
  unsigned int* flags = (unsigned int*)((char*)d_ws + 65536 + 262144); // 4 KB, poison-reset

  qprep_kernel<<<64, 256, 0, stream>>>(q, qs, (float*)d_out);
  fused_kernel<<<C + 1, 256, 0, stream>>>(p, qs, scores, flags, (float*)d_out);
}

// Round 9
// 93.068 us; speedup vs baseline: 1.2874x; 1.2874x over previous
//
#include <hip/hip_runtime.h>

#define BQ 32
#define H  128
#define C  512
#define D  128

typedef _Float16 half8v __attribute__((ext_vector_type(8)));
typedef float floatx4 __attribute__((ext_vector_type(4)));

// ---------------------------------------------------------------------------
// VERBATIM revert to the session-best baseline (harness-verified 92.9/93.8us).
// Session ledger (r0-r8): total = ~63us fixed (43 fill + ~20 graph overhead,
// launch-count-free) + kernel sum (~31us).  Fusion attempts (coop grid.sync,
// spin-consumer, if/else) all regressed: the scores body's ~150-VGPR MFMA
// ring collapses regalloc in any wrapper (measured VGPR 96/80/92/80).  Safe
// rearrangements (R=2/4/8 Q-reuse, 1-4 waves/SIMD) all within +4..6us of
// this configuration.  This 3-kernel form is the measured optimum.
// ---------------------------------------------------------------------------

// Kernel 0: Q fp32 -> fp16 fragments for 16x16x32 MFMA B-operand, plus zero
// the loss accumulator (d_out).
// Frag index (half8 units): ((b*4 + kb)*2 + sh)*64 + lane
//   elem[n = lane&15][k = kb*32 + (lane>>4)*8 + j],  s = sh*16 + n
__global__ __launch_bounds__(256) void qprep_kernel(const float* __restrict__ q,
                                                    _Float16* __restrict__ qs,
                                                    float* __restrict__ out) {
  int t = blockIdx.x * 256 + threadIdx.x;     // 0..16383, one half8 frag each
  if (t == 0) out[0] = 0.0f;
  int lane = t & 63;
  int sh   = (t >> 6) & 1;
  int kb   = (t >> 7) & 3;
  int b    = t >> 9;
  int s    = sh * 16 + (lane & 15);
  int h    = kb * 32 + (lane >> 4) * 8;
  const float* src = q + ((b * 32 + s) * H + h);
  float4 v0 = *(const float4*)src;
  float4 v1 = *(const float4*)(src + 4);
  half8v o = { (_Float16)v0.x, (_Float16)v0.y, (_Float16)v0.z, (_Float16)v0.w,
               (_Float16)v1.x, (_Float16)v1.y, (_Float16)v1.z, (_Float16)v1.w };
  *(half8v*)(qs + (size_t)t * 8) = o;
}

// Kernel 1: block c (256 thr, 4 waves) -> scores[b][c].
// 16x16x32 f16 MFMA, transposed: A = P_c (m = d), B = Q_b (n = s).
// Wave w: d-half dq=w&1 (64 rows = 4 m-tiles), s-half sh=w>>1 (16 cols).
// Q prefetch: qb[3] round-robin ring, distance 2, fully unrolled so all
// register-array indices are compile-time constants.
// grid 512, __launch_bounds__(256,2): 2 blocks/CU, 2 waves/SIMD, no spill.
__global__ __launch_bounds__(256, 2) void scores_kernel(const float* __restrict__ pos,
                                                        const _Float16* __restrict__ qs,
                                                        float* __restrict__ scores) {
  const int c    = blockIdx.x;
  const int tid  = threadIdx.x;
  const int w    = tid >> 6;
  const int lane = tid & 63;
  const int dq   = w & 1;            // d-half
  const int sh   = w >> 1;           // s-half
  const int quad = lane >> 4;
  const int nrow = lane & 15;

  __shared__ float pmm[BQ][4][16];   // [b][wave][s_local]  8 KB

  const half8v* qf = (const half8v*)qs;
  const float*  pc = pos + (size_t)c * (D * H);

  half8v  pa[4][4];    // P_c A-frags [mt][kb]  (64 VGPRs)
  half8v  qb[3][4];    // Q B-frags, round-robin, prefetch distance 2 (48 VGPRs)
  floatx4 acc[2][4];   // [buf][mt] (32 VGPRs)
  floatx4 zc = {0.f, 0.f, 0.f, 0.f};   // persistent zero C-operand

  // P_c A-frags: A[m = dq*64 + mt*16 + nrow][k = kb*32 + quad*8 + j]
#pragma unroll
  for (int kb = 0; kb < 4; ++kb)
#pragma unroll
    for (int mt = 0; mt < 4; ++mt) {
      const float* src = pc + ((dq * 64 + mt * 16 + nrow) * H + kb * 32 + quad * 8);
      float4 v0 = *(const float4*)src;
      float4 v1 = *(const float4*)(src + 4);
      half8v f = { (_Float16)v0.x, (_Float16)v0.y, (_Float16)v0.z, (_Float16)v0.w,
                   (_Float16)v1.x, (_Float16)v1.y, (_Float16)v1.z, (_Float16)v1.w };
      pa[mt][kb] = f;
    }

  // Q fragments for b=0,1 (prefetch pipeline primed to depth 2)
#pragma unroll
  for (int kb = 0; kb < 4; ++kb) qb[0][kb] = qf[(kb * 2 + sh) * 64 + lane];
#pragma unroll
  for (int kb = 0; kb < 4; ++kb) qb[1][kb] = qf[((4 + kb) * 2 + sh) * 64 + lane];

  // Reduce: max over this wave's 64 d-rows for each of its 16 s.
  // C/D: col s_local = lane&15, row d_local = quad*4 + r  [m89/m91]
  auto reduce_store = [&](int b, floatx4 (&a)[4]) {
    float m0 = fmaxf(fmaxf(a[0][0], a[0][1]), fmaxf(a[0][2], a[0][3]));
    float m1 = fmaxf(fmaxf(a[1][0], a[1][1]), fmaxf(a[1][2], a[1][3]));
    float m2 = fmaxf(fmaxf(a[2][0], a[2][1]), fmaxf(a[2][2], a[2][3]));
    float m3 = fmaxf(fmaxf(a[3][0], a[3][1]), fmaxf(a[3][2], a[3][3]));
    float m  = fmaxf(fmaxf(m0, m1), fmaxf(m2, m3));
    m = fmaxf(m, __shfl_xor(m, 16));
    m = fmaxf(m, __shfl_xor(m, 32));
    if (lane < 16) pmm[b][w][lane] = m;
  };

  // main loop: prefetch b+2 (distance 2), compute b, reduce b-1
#pragma unroll
  for (int b = 0; b < BQ; ++b) {
    const int cur = b & 1;
    if (b + 2 < BQ) {
      half8v* dst = qb[(b + 2) % 3];
#pragma unroll
      for (int kb = 0; kb < 4; ++kb) dst[kb] = qf[(((b + 2) * 4 + kb) * 2 + sh) * 64 + lane];
    }
    const half8v* qc = qb[b % 3];
#pragma unroll
    for (int mt = 0; mt < 4; ++mt)
      acc[cur][mt] = __builtin_amdgcn_mfma_f32_16x16x32_f16(pa[mt][0], qc[0], zc, 0, 0, 0);
#pragma unroll
    for (int kb = 1; kb < 4; ++kb)
#pragma unroll
      for (int mt = 0; mt < 4; ++mt)
        acc[cur][mt] = __builtin_amdgcn_mfma_f32_16x16x32_f16(pa[mt][kb], qc[kb], acc[cur][mt], 0, 0, 0);
    if (b > 0) reduce_store(b - 1, acc[cur ^ 1]);
  }
  reduce_store(BQ - 1, acc[1]);   // b=31 landed in acc[1]

  __syncthreads();

  // epilogue: scores[b][c] = 50 * sum_s max over the two d-half waves
  {
    int b  = tid >> 3;
    int t8 = tid & 7;
    float v = 0.f;
#pragma unroll
    for (int j = 0; j < 4; ++j) {
      int s  = t8 * 4 + j;
      int h2 = s >> 4, sl = s & 15;
      v += fmaxf(pmm[b][2 * h2][sl], pmm[b][2 * h2 + 1][sl]);
    }
    v += __shfl_xor(v, 1);
    v += __shfl_xor(v, 2);
    v += __shfl_xor(v, 4);
    if (t8 == 0) scores[b * C + c] = v * 50.0f;   // / TEMPERATURE
  }
}

// Kernel 2: one block per b; loss += (logsumexp_c - scores[b][0]) / 32
__global__ __launch_bounds__(256) void loss_kernel(const float* __restrict__ scores,
                                                   float* __restrict__ out) {
  __shared__ float red[8];
  const int b = blockIdx.x, tid = threadIdx.x, w = tid >> 6, lane = tid & 63;
  const float* row = scores + b * C;
  float x0 = row[tid], x1 = row[tid + 256];
  float mx = fmaxf(x0, x1);
#pragma unroll
  for (int off = 1; off < 64; off <<= 1) mx = fmaxf(mx, __shfl_xor(mx, off));
  if (lane == 0) red[w] = mx;
  __syncthreads();
  float bmax = fmaxf(fmaxf(red[0], red[1]), fmaxf(red[2], red[3]));
  float e = __expf(x0 - bmax) + __expf(x1 - bmax);
#pragma unroll
  for (int off = 1; off < 64; off <<= 1) e += __shfl_xor(e, off);
  if (lane == 0) red[4 + w] = e;
  __syncthreads();
  if (tid == 0) {
    float s = red[4] + red[5] + red[6] + red[7];
    atomicAdd(out, (bmax + __logf(s) - row[0]) * (1.0f / 32.0f));
  }
}

extern "C" void kernel_launch(void* const* d_in, const int* in_sizes, int n_in,
                              void* d_out, int out_size, void* d_ws, size_t ws_size,
                              hipStream_t stream) {
  const float* q = (const float*)d_in[0];   // [32,32,128] fp32
  const float* p = (const float*)d_in[1];   // [512,128,128] fp32
  float* scores  = (float*)d_ws;                              // 64 KB
  _Float16* qs   = (_Float16*)((char*)d_ws + 65536);          // 256 KB fp16 frags

  qprep_kernel<<<64, 256, 0, stream>>>(q, qs, (float*)d_out);
  scores_kernel<<<C, 256, 0, stream>>>(p, qs, scores);
  loss_kernel<<<32, 256, 0, stream>>>(scores, (float*)d_out);
}